// Round 13
// baseline (426.994 us; speedup 1.0000x reference)
//
#include <hip/hip_runtime.h>
#include <math.h>

#define Bsz    2048
#define Ccnt   100000
#define Dd     128
#define CT     128                 // classes per margin block
#define NMBLK  782                 // ceil(Ccnt/CT)
#define NCHUNK (Bsz / 32)          // 64 sample chunks of 32
#define GRID_G 3200                // 400 groups of 8
#define SBLKS  2400                // scale blocks (300 groups x 8)
#define N4     (Bsz * (Ccnt / 4))  // 51.2M float4 elements

typedef short  bf16x8  __attribute__((ext_vector_type(8)));
typedef float  f32x16  __attribute__((ext_vector_type(16)));
typedef float  f32x4   __attribute__((ext_vector_type(4)));

// ---- order-preserving float <-> uint encoding for atomicMax ----
static __device__ __forceinline__ unsigned int enc_f32(float f) {
    unsigned int u = __float_as_uint(f);
    return (u & 0x80000000u) ? ~u : (u | 0x80000000u);
}
static __device__ __forceinline__ float dec_f32(unsigned int u) {
    unsigned int b = (u & 0x80000000u) ? (u & 0x7fffffffu) : ~u;
    return __uint_as_float(b);
}
// fp32 -> bf16 round-to-nearest-even
static __device__ __forceinline__ unsigned short f2bf(float f) {
    unsigned int u = __float_as_uint(f);
    unsigned int r = ((u >> 16) & 1u) + 0x7fffu;
    return (unsigned short)((u + r) >> 16);
}

// ---- prep: pack Q = wnorm[labels] as bf16 in MFMA B-fragment order.
// Fragment (p,t), lane l: Q[s = p*32+(l&31)][d = (l>>5)*8 + t*16 .. +8].
__global__ __launch_bounds__(256) void prep_kernel(
    const int* __restrict__ labels,
    const float* __restrict__ wnorm,
    bf16x8* __restrict__ qpk,
    unsigned int* __restrict__ maxbuf)
{
    int tid = blockIdx.x * 256 + threadIdx.x;   // 32768 threads
    if (tid < Bsz) maxbuf[tid] = 0u;            // reset running-max (enc space)
    int b   = tid >> 4;                         // sample
    int c8  = (tid & 15) << 3;                  // first of this thread's 8 dims
    if (b >= Bsz) return;
    int lab = labels[b];
    if (lab < 0) lab = 0;
    const float* src = wnorm + (size_t)lab * Dd + c8;
    float4 u = *reinterpret_cast<const float4*>(src);
    float4 v = *reinterpret_cast<const float4*>(src + 4);
    unsigned short o[8] = { f2bf(u.x), f2bf(u.y), f2bf(u.z), f2bf(u.w),
                            f2bf(v.x), f2bf(v.y), f2bf(v.z), f2bf(v.w) };
    int p = b >> 5, t = c8 >> 4, l = ((c8 >> 3) & 1) * 32 + (b & 31);
    qpk[(size_t)(p * 8 + t) * 64 + l] = *reinterpret_cast<bf16x8*>(o);
}

// ---- margin role (round-6/10 verified: ~78us standalone steady-state) ----
template<bool EDGE>
__device__ __forceinline__ void margin_chunks(
    const int* __restrict__ labels,
    const bf16x8* __restrict__ qpk,
    const bf16x8 (&afr)[8], int base_c, int lane,
    unsigned int* smax)
{
    const int lm  = lane & 31;
    const int lim = Ccnt - base_c;   // only used when EDGE

    bf16x8 bcur[8];
#pragma unroll
    for (int t = 0; t < 8; ++t)
        bcur[t] = qpk[t * 64 + lane];

    for (int ch = 0; ch < NCHUNK; ++ch) {
        const int s = ch * 32 + lm;

        bf16x8 bnxt[8];
        if (ch + 1 < NCHUNK) {
            const bf16x8* qw = qpk + (size_t)(ch + 1) * 8 * 64;
#pragma unroll
            for (int t = 0; t < 8; ++t)
                bnxt[t] = qw[t * 64 + lane];
        }

        f32x16 acc0 = {}, acc1 = {};
#pragma unroll
        for (int t = 0; t < 8; t += 2) {
            acc0 = __builtin_amdgcn_mfma_f32_32x32x16_bf16(afr[t],     bcur[t],     acc0, 0, 0, 0);
            acc1 = __builtin_amdgcn_mfma_f32_32x32x16_bf16(afr[t + 1], bcur[t + 1], acc1, 0, 0, 0);
        }

        const int rel = labels[s] - base_c;

        float v[16];
#pragma unroll
        for (int r = 0; r < 16; ++r) {
            const int row = (r & 3) + 8 * (r >> 2);
            float tv = acc0[r] + acc1[r];
            bool kill = (rel == row);
            if (EDGE) kill = kill || (row >= lim);
            v[r] = kill ? -3.0f : tv;
        }
#pragma unroll
        for (int st = 1; st < 16; st <<= 1)
#pragma unroll
            for (int r = 0; r < 16; r += 2 * st)
                v[r] = fmaxf(v[r], v[r + st]);
        float m = fmaxf(v[0], __shfl_xor(v[0], 32));
        if (lane < 32) atomicMax(&smax[s], enc_f32(m));

#pragma unroll
        for (int t = 0; t < 8; ++t) bcur[t] = bnxt[t];
    }
}

__device__ __forceinline__ void margin_body(
    int mb,
    const int* __restrict__ labels,
    const float* __restrict__ wnorm,
    const bf16x8* __restrict__ qpk,
    unsigned int* __restrict__ maxbuf)
{
    __shared__ unsigned int smax[Bsz];
    for (int i = threadIdx.x; i < Bsz; i += 256) smax[i] = 0u;
    __syncthreads();

    const int wave  = threadIdx.x >> 6;
    const int lane  = threadIdx.x & 63;
    const int h     = lane >> 5;
    const int lm    = lane & 31;
    const int cbase = mb * CT + wave * 32;
    const int cls   = cbase + lm;
    const bool cvalid = cls < Ccnt;

    bf16x8 afr[8];
    {
        const float* wr = wnorm + (size_t)(cvalid ? cls : 0) * Dd + h * 8;
#pragma unroll
        for (int t = 0; t < 8; ++t) {
            float4 u = *reinterpret_cast<const float4*>(wr + t * 16);
            float4 v = *reinterpret_cast<const float4*>(wr + t * 16 + 4);
            if (!cvalid) { u = make_float4(0,0,0,0); v = make_float4(0,0,0,0); }
            unsigned short o[8] = { f2bf(u.x), f2bf(u.y), f2bf(u.z), f2bf(u.w),
                                    f2bf(v.x), f2bf(v.y), f2bf(v.z), f2bf(v.w) };
            afr[t] = *reinterpret_cast<bf16x8*>(o);
        }
    }
    const int base_c = cbase + 4 * h;

    if (mb == NMBLK - 1)
        margin_chunks<true >(labels, qpk, afr, base_c, lane, smax);
    else
        margin_chunks<false>(labels, qpk, afr, base_c, lane, smax);

    __syncthreads();
    for (int i = threadIdx.x; i < Bsz; i += 256)
        atomicMax(&maxbuf[i], smax[i]);
}

// ---- scale role: out = logits * 64, nontemporal x2 ----
__device__ __forceinline__ void scale_body(
    int sidx, const f32x4* __restrict__ in, f32x4* __restrict__ out)
{
    const int stride = SBLKS * 512;
    for (int i = (sidx * 256 + (int)threadIdx.x) * 2; i < N4; i += stride) {
        f32x4 a = __builtin_nontemporal_load(in + i);
        f32x4 b = __builtin_nontemporal_load(in + i + 1);   // N4 is even
        a *= 64.f;
        b *= 64.f;
        __builtin_nontemporal_store(a, out + i);
        __builtin_nontemporal_store(b, out + i + 1);
    }
}

// ---- fused kernel. Role by GROUP of 8 consecutive bids (XCD-even: each
// group spans bid%8 = 0..7). Margin groups only in the FIRST 300 groups at
// 1-in-3 density (g%3==2): margin starts early and fully drains before the
// scale tail -- no exposed margin after HBM streaming ends (round-12's
// uniform interleave left a ~100us margin tail at the end of the grid).
__global__ __launch_bounds__(256, 3) void mega_kernel(
    const int* __restrict__ labels,
    const float* __restrict__ wnorm,
    const bf16x8* __restrict__ qpk,
    unsigned int* __restrict__ maxbuf,
    const f32x4* __restrict__ in,
    f32x4* __restrict__ out)
{
    const int bid = blockIdx.x;
    const int g   = bid >> 3;                 // group index, 0..399
    if (g < 300 && (g % 3) == 2) {            // margin group (100 of them)
        int mb = (g / 3) * 8 + (bid & 7);     // 0..799
        if (mb < NMBLK)
            margin_body(mb, labels, wnorm, qpk, maxbuf);
        // mb 782..799: 18 idle blocks (negligible)
    } else {                                  // scale group (300 of them)
        int sg = (g < 300) ? (g - (g + 1) / 3) : (200 + (g - 300));
        scale_body(sg * 8 + (bid & 7), in, out);
    }
}

// ---- per-sample target fixup ----
__global__ void fixup_kernel(const float* __restrict__ logits,
                             const int* __restrict__ labels,
                             const unsigned int* __restrict__ maxbuf,
                             float* __restrict__ out)
{
    int b = blockIdx.x * blockDim.x + threadIdx.x;
    if (b >= Bsz) return;
    int lab = labels[b];
    if (lab < 0) return;
    float mx = dec_f32(maxbuf[b]);
    mx = fminf(fmaxf(mx, -1.f), 1.f);
    float theta  = acosf(mx);
    float d      = theta - 1.0f;                                 // K1
    float smooth = 0.012f / powf(1.0f + fabsf(d) * 20.0f, 1.1f); // 0.03*K3
    float margin = fmaxf(d, 0.f) * 0.1f + 0.4f + smooth;         // K2, K3
    size_t off = (size_t)b * Ccnt + lab;
    float x = logits[off];
    out[off] = cosf(acosf(x) + margin) * 64.0f;                  // S
}

extern "C" void kernel_launch(void* const* d_in, const int* in_sizes, int n_in,
                              void* d_out, int out_size, void* d_ws, size_t ws_size,
                              hipStream_t stream)
{
    const float* logits = (const float*)d_in[0];
    const int*   labels = (const int*)d_in[1];
    const float* wnorm  = (const float*)d_in[2];
    float* out = (float*)d_out;

    unsigned int* maxbuf = (unsigned int*)d_ws;                 // 8 KB
    bf16x8*       qpk    = (bf16x8*)((char*)d_ws + 8192);       // 512 KB

    prep_kernel<<<(Bsz * (Dd / 8) + 255) / 256, 256, 0, stream>>>(
        labels, wnorm, qpk, maxbuf);

    mega_kernel<<<GRID_G, 256, 0, stream>>>(
        labels, wnorm, qpk, maxbuf,
        (const f32x4*)logits, (f32x4*)out);

    fixup_kernel<<<(Bsz + 255) / 256, 256, 0, stream>>>(
        logits, labels, maxbuf, out);
}

// Round 15
// 423.773 us; speedup vs baseline: 1.0076x; 1.0076x over previous
//
#include <hip/hip_runtime.h>
#include <math.h>

#define Bsz    2048
#define Ccnt   100000
#define Dd     128
#define CT     128                 // classes per margin block
#define NMBLK  782                 // ceil(Ccnt/CT)
#define NCHUNK (Bsz / 32)          // 64 sample chunks of 32
#define GRID_G 3200                // 400 groups of 8; every 4th group = margin
#define SBLKS  2400                // scale blocks (300 groups x 8)
#define N4     (Bsz * (Ccnt / 4))  // 51.2M float4 elements

typedef short  bf16x8  __attribute__((ext_vector_type(8)));
typedef float  f32x16  __attribute__((ext_vector_type(16)));
typedef float  f32x4   __attribute__((ext_vector_type(4)));

// ---- order-preserving float <-> uint encoding for atomicMax ----
static __device__ __forceinline__ unsigned int enc_f32(float f) {
    unsigned int u = __float_as_uint(f);
    return (u & 0x80000000u) ? ~u : (u | 0x80000000u);
}
static __device__ __forceinline__ float dec_f32(unsigned int u) {
    unsigned int b = (u & 0x80000000u) ? (u & 0x7fffffffu) : ~u;
    return __uint_as_float(b);
}
// fp32 -> bf16 round-to-nearest-even
static __device__ __forceinline__ unsigned short f2bf(float f) {
    unsigned int u = __float_as_uint(f);
    unsigned int r = ((u >> 16) & 1u) + 0x7fffu;
    return (unsigned short)((u + r) >> 16);
}

// ---- prep: pack Q = wnorm[labels] as bf16 in MFMA B-fragment order.
// Fragment (p,t), lane l: Q[s = p*32+(l&31)][d = (l>>5)*8 + t*16 .. +8].
__global__ __launch_bounds__(256) void prep_kernel(
    const int* __restrict__ labels,
    const float* __restrict__ wnorm,
    bf16x8* __restrict__ qpk,
    unsigned int* __restrict__ maxbuf)
{
    int tid = blockIdx.x * 256 + threadIdx.x;   // 32768 threads
    if (tid < Bsz) maxbuf[tid] = 0u;            // reset running-max (enc space)
    int b   = tid >> 4;                         // sample
    int c8  = (tid & 15) << 3;                  // first of this thread's 8 dims
    if (b >= Bsz) return;
    int lab = labels[b];
    if (lab < 0) lab = 0;
    const float* src = wnorm + (size_t)lab * Dd + c8;
    float4 u = *reinterpret_cast<const float4*>(src);
    float4 v = *reinterpret_cast<const float4*>(src + 4);
    unsigned short o[8] = { f2bf(u.x), f2bf(u.y), f2bf(u.z), f2bf(u.w),
                            f2bf(v.x), f2bf(v.y), f2bf(v.z), f2bf(v.w) };
    int p = b >> 5, t = c8 >> 4, l = ((c8 >> 3) & 1) * 32 + (b & 31);
    qpk[(size_t)(p * 8 + t) * 64 + l] = *reinterpret_cast<bf16x8*>(o);
}

// ---- margin role, slimmed for <=128 VGPR (4 blocks/CU with scale):
// direct loads (TLP covers L2 latency), single acc chain, 4-temp max.
template<bool EDGE>
__device__ __forceinline__ void margin_chunks(
    const int* __restrict__ labels,
    const bf16x8* __restrict__ qpk,
    const bf16x8 (&afr)[8], int base_c, int lane,
    unsigned int* smax)
{
    const int lm  = lane & 31;
    const int lim = Ccnt - base_c;   // only used when EDGE

    for (int ch = 0; ch < NCHUNK; ++ch) {
        const int s = ch * 32 + lm;
        const bf16x8* qw = qpk + (size_t)ch * 512;
        bf16x8 b0 = qw[0 * 64 + lane], b1 = qw[1 * 64 + lane];
        bf16x8 b2 = qw[2 * 64 + lane], b3 = qw[3 * 64 + lane];
        bf16x8 b4 = qw[4 * 64 + lane], b5 = qw[5 * 64 + lane];
        bf16x8 b6 = qw[6 * 64 + lane], b7 = qw[7 * 64 + lane];

        f32x16 acc = {};
        acc = __builtin_amdgcn_mfma_f32_32x32x16_bf16(afr[0], b0, acc, 0, 0, 0);
        acc = __builtin_amdgcn_mfma_f32_32x32x16_bf16(afr[1], b1, acc, 0, 0, 0);
        acc = __builtin_amdgcn_mfma_f32_32x32x16_bf16(afr[2], b2, acc, 0, 0, 0);
        acc = __builtin_amdgcn_mfma_f32_32x32x16_bf16(afr[3], b3, acc, 0, 0, 0);
        acc = __builtin_amdgcn_mfma_f32_32x32x16_bf16(afr[4], b4, acc, 0, 0, 0);
        acc = __builtin_amdgcn_mfma_f32_32x32x16_bf16(afr[5], b5, acc, 0, 0, 0);
        acc = __builtin_amdgcn_mfma_f32_32x32x16_bf16(afr[6], b6, acc, 0, 0, 0);
        acc = __builtin_amdgcn_mfma_f32_32x32x16_bf16(afr[7], b7, acc, 0, 0, 0);

        const int rel = labels[s] - base_c;

        float mm0 = -3.0f, mm1 = -3.0f, mm2 = -3.0f, mm3 = -3.0f;
#pragma unroll
        for (int r = 0; r < 16; ++r) {
            const int row = (r & 3) + 8 * (r >> 2);
            float tv = acc[r];
            bool kill = (rel == row);
            if (EDGE) kill = kill || (row >= lim);
            tv = kill ? -3.0f : tv;
            if ((r & 3) == 0) mm0 = fmaxf(mm0, tv);
            if ((r & 3) == 1) mm1 = fmaxf(mm1, tv);
            if ((r & 3) == 2) mm2 = fmaxf(mm2, tv);
            if ((r & 3) == 3) mm3 = fmaxf(mm3, tv);
        }
        float m = fmaxf(fmaxf(mm0, mm1), fmaxf(mm2, mm3));
        m = fmaxf(m, __shfl_xor(m, 32));    // join the two K-half lane sets
        if (lane < 32) atomicMax(&smax[s], enc_f32(m));
    }
}

__device__ __forceinline__ void margin_body(
    int mb,
    const int* __restrict__ labels,
    const float* __restrict__ wnorm,
    const bf16x8* __restrict__ qpk,
    unsigned int* __restrict__ maxbuf)
{
    __shared__ unsigned int smax[Bsz];
    for (int i = threadIdx.x; i < Bsz; i += 256) smax[i] = 0u;
    __syncthreads();

    const int wave  = threadIdx.x >> 6;
    const int lane  = threadIdx.x & 63;
    const int h     = lane >> 5;
    const int lm    = lane & 31;
    const int cbase = mb * CT + wave * 32;
    const int cls   = cbase + lm;
    const bool cvalid = cls < Ccnt;

    bf16x8 afr[8];
    {
        const float* wr = wnorm + (size_t)(cvalid ? cls : 0) * Dd + h * 8;
#pragma unroll
        for (int t = 0; t < 8; ++t) {
            float4 u = *reinterpret_cast<const float4*>(wr + t * 16);
            float4 v = *reinterpret_cast<const float4*>(wr + t * 16 + 4);
            if (!cvalid) { u = make_float4(0,0,0,0); v = make_float4(0,0,0,0); }
            unsigned short o[8] = { f2bf(u.x), f2bf(u.y), f2bf(u.z), f2bf(u.w),
                                    f2bf(v.x), f2bf(v.y), f2bf(v.z), f2bf(v.w) };
            afr[t] = *reinterpret_cast<bf16x8*>(o);
        }
    }
    const int base_c = cbase + 4 * h;

    if (mb == NMBLK - 1)
        margin_chunks<true >(labels, qpk, afr, base_c, lane, smax);
    else
        margin_chunks<false>(labels, qpk, afr, base_c, lane, smax);

    __syncthreads();
    for (int i = threadIdx.x; i < Bsz; i += 256)
        atomicMax(&maxbuf[i], smax[i]);
}

// ---- scale role: out = logits * 64, nontemporal x2 ----
__device__ __forceinline__ void scale_body(
    int sidx, const f32x4* __restrict__ in, f32x4* __restrict__ out)
{
    const int stride = SBLKS * 512;
    for (int i = (sidx * 256 + (int)threadIdx.x) * 2; i < N4; i += stride) {
        f32x4 a = __builtin_nontemporal_load(in + i);
        f32x4 b = __builtin_nontemporal_load(in + i + 1);   // N4 is even
        a *= 64.f;
        b *= 64.f;
        __builtin_nontemporal_store(a, out + i);
        __builtin_nontemporal_store(b, out + i + 1);
    }
}

// ---- fused kernel: round-12 group map + (256,4) occupancy.
// Role by GROUP of 8 consecutive bids (XCD-even); every 4th group (g%4==3)
// is margin. Scale index: margin groups before group g = (g+1)>>2 exactly
// (round-14 bug: used (g>>2)+1, off by one for g%4<3 -> skipped 8 blocks).
__global__ __launch_bounds__(256, 4) void mega_kernel(
    const int* __restrict__ labels,
    const float* __restrict__ wnorm,
    const bf16x8* __restrict__ qpk,
    unsigned int* __restrict__ maxbuf,
    const f32x4* __restrict__ in,
    f32x4* __restrict__ out)
{
    const int bid = blockIdx.x;
    const int g   = bid >> 3;                 // group index, 0..399
    if ((g & 3) == 3) {                       // margin group (100 of them)
        int mb = (g >> 2) * 8 + (bid & 7);    // 0..799
        if (mb < NMBLK)
            margin_body(mb, labels, wnorm, qpk, maxbuf);
        // mb 782..799: 18 idle blocks (negligible)
    } else {                                  // scale group (300 of them)
        int sidx = bid - (((g + 1) >> 2) << 3);   // bijective onto 0..2399
        scale_body(sidx, in, out);
    }
}

// ---- per-sample target fixup ----
__global__ void fixup_kernel(const float* __restrict__ logits,
                             const int* __restrict__ labels,
                             const unsigned int* __restrict__ maxbuf,
                             float* __restrict__ out)
{
    int b = blockIdx.x * blockDim.x + threadIdx.x;
    if (b >= Bsz) return;
    int lab = labels[b];
    if (lab < 0) return;
    float mx = dec_f32(maxbuf[b]);
    mx = fminf(fmaxf(mx, -1.f), 1.f);
    float theta  = acosf(mx);
    float d      = theta - 1.0f;                                 // K1
    float smooth = 0.012f / powf(1.0f + fabsf(d) * 20.0f, 1.1f); // 0.03*K3
    float margin = fmaxf(d, 0.f) * 0.1f + 0.4f + smooth;         // K2, K3
    size_t off = (size_t)b * Ccnt + lab;
    float x = logits[off];
    out[off] = cosf(acosf(x) + margin) * 64.0f;                  // S
}

extern "C" void kernel_launch(void* const* d_in, const int* in_sizes, int n_in,
                              void* d_out, int out_size, void* d_ws, size_t ws_size,
                              hipStream_t stream)
{
    const float* logits = (const float*)d_in[0];
    const int*   labels = (const int*)d_in[1];
    const float* wnorm  = (const float*)d_in[2];
    float* out = (float*)d_out;

    unsigned int* maxbuf = (unsigned int*)d_ws;                 // 8 KB
    bf16x8*       qpk    = (bf16x8*)((char*)d_ws + 8192);       // 512 KB

    prep_kernel<<<(Bsz * (Dd / 8) + 255) / 256, 256, 0, stream>>>(
        labels, wnorm, qpk, maxbuf);

    mega_kernel<<<GRID_G, 256, 0, stream>>>(
        labels, wnorm, qpk, maxbuf,
        (const f32x4*)logits, (f32x4*)out);

    fixup_kernel<<<(Bsz + 255) / 256, 256, 0, stream>>>(
        logits, labels, maxbuf, out);
}